// Round 6
// baseline (330.154 us; speedup 1.0000x reference)
//
#include <hip/hip_runtime.h>

// 4-bit ripple-borrow subtractor, one thread per row (flat R0 shape).
// A,B: (N,4) float32 with values in {0.0, 1.0}.
// Out: [ diffs (N,4) | borrow (N,1) ] flat float32.
// Index 3 is the LSB (reference loops i = 3..0).
//
// R6: directed MALL retention. R5 was fully-streaming (NT everything):
// 436 MB HBM/iter, 256 MB Infinity Cache idle. A (134 MB) fits in MALL.
// Change one variable vs R5: A loads are now NORMAL (allocating); B loads
// and both stores stay NT so nothing competes for MALL capacity.
// Steady state: A from MALL, HBM = B(134) + writes(168) = 302 MB -> ~48us
// floor. Risk: harness 671MB fill resets may evict A between iterations ->
// neutral outcome (R0's 50% FETCH retention suggests they don't).

constexpr int BLOCK = 256;

typedef float v4f __attribute__((ext_vector_type(4)));

__global__ __launch_bounds__(BLOCK) void Subtractor4Bit_kernel(
    const float* __restrict__ A,
    const float* __restrict__ B,
    float* __restrict__ res,
    float* __restrict__ borrow_out,
    int n_rows)
{
    int i = blockIdx.x * BLOCK + threadIdx.x;
    if (i >= n_rows) return;

    // A: normal load -> allocates in MALL (134 MB, fits in 256 MB).
    v4f a = *((const v4f*)A + i);
    // B: NT load -> streams from HBM, no MALL allocation.
    v4f b = __builtin_nontemporal_load((const v4f*)B + i);

    // Convert to 0/1 ints (inputs are exactly 0.0f or 1.0f).
    int a0 = (a[0] != 0.0f), a1 = (a[1] != 0.0f), a2 = (a[2] != 0.0f), a3 = (a[3] != 0.0f);
    int b0 = (b[0] != 0.0f), b1 = (b[1] != 0.0f), b2 = (b[2] != 0.0f), b3 = (b[3] != 0.0f);

    int bor = 0;
    // i = 3 (LSB)
    int d3 = a3 ^ b3 ^ bor;
    int na = 1 - a3;
    bor = (na & b3) | (na & bor) | (b3 & bor);
    // i = 2
    int d2 = a2 ^ b2 ^ bor;
    na = 1 - a2;
    bor = (na & b2) | (na & bor) | (b2 & bor);
    // i = 1
    int d1 = a1 ^ b1 ^ bor;
    na = 1 - a1;
    bor = (na & b1) | (na & bor) | (b1 & bor);
    // i = 0 (MSB)
    int d0 = a0 ^ b0 ^ bor;
    na = 1 - a0;
    bor = (na & b0) | (na & bor) | (b0 & bor);

    v4f r;
    r[0] = (float)d0;
    r[1] = (float)d1;
    r[2] = (float)d2;
    r[3] = (float)d3;

    __builtin_nontemporal_store(r, (v4f*)res + i);
    __builtin_nontemporal_store((float)bor, borrow_out + i);
}

extern "C" void kernel_launch(void* const* d_in, const int* in_sizes, int n_in,
                              void* d_out, int out_size, void* d_ws, size_t ws_size,
                              hipStream_t stream)
{
    const float* A = (const float*)d_in[0];
    const float* B = (const float*)d_in[1];
    float* out = (float*)d_out;

    int n_rows = in_sizes[0] / 4;              // (N,4) -> N rows
    float* res = out;                          // first 4*N floats: diffs
    float* borrow = out + (size_t)n_rows * 4;  // last N floats: borrow

    int grid = (n_rows + BLOCK - 1) / BLOCK;
    Subtractor4Bit_kernel<<<grid, BLOCK, 0, stream>>>(A, B, res, borrow, n_rows);
}

// Round 7
// 323.604 us; speedup vs baseline: 1.0202x; 1.0202x over previous
//
#include <hip/hip_runtime.h>

// 4-bit ripple-borrow subtractor.
// A,B: (N,4) float32 with values in {0.0, 1.0}.
// Out: [ diffs (N,4) | borrow (N,1) ] flat float32.
// Index 3 is the LSB (reference loops i = 3..0).
//
// R7: persistent grid-stride + flat 1-row-per-iteration + NT everything.
// Evidence chain: R6 proved HBM bytes aren't the limit (A served from MALL,
// -134MB HBM traffic, zero time change) -> delivered-BW request path caps
// at ~4.5 TB/s. Remaining structural delta vs the 6.29 TB/s m13 copy bench:
// 32768 one-shot blocks (store-drain waitcnt before every s_endpgm +
// dispatch churn, 71% avg occupancy) vs a persistent loop where iter k+1's
// loads overlap iter k's stores. R3's persistent attempt was confounded
// (normal loads = MALL thrash + 4-deep load clumps); this is the clean cell:
// NO hand-batching, NT loads+stores, simple loop.

constexpr int BLOCK = 256;
constexpr int GRID  = 2048;   // 8 blocks/CU * 256 CUs

typedef float v4f __attribute__((ext_vector_type(4)));

__global__ __launch_bounds__(BLOCK) void Subtractor4Bit_kernel(
    const float* __restrict__ A,
    const float* __restrict__ B,
    float* __restrict__ res,
    float* __restrict__ borrow_out,
    int n_rows)
{
    const int stride = gridDim.x * BLOCK;

    for (int i = blockIdx.x * BLOCK + threadIdx.x; i < n_rows; i += stride) {
        v4f a = __builtin_nontemporal_load((const v4f*)A + i);
        v4f b = __builtin_nontemporal_load((const v4f*)B + i);

        // Convert to 0/1 ints (inputs are exactly 0.0f or 1.0f).
        int a0 = (a[0] != 0.0f), a1 = (a[1] != 0.0f), a2 = (a[2] != 0.0f), a3 = (a[3] != 0.0f);
        int b0 = (b[0] != 0.0f), b1 = (b[1] != 0.0f), b2 = (b[2] != 0.0f), b3 = (b[3] != 0.0f);

        int bor = 0;
        // bit 3 (LSB)
        int d3 = a3 ^ b3 ^ bor;
        int na = 1 - a3;
        bor = (na & b3) | (na & bor) | (b3 & bor);
        // bit 2
        int d2 = a2 ^ b2 ^ bor;
        na = 1 - a2;
        bor = (na & b2) | (na & bor) | (b2 & bor);
        // bit 1
        int d1 = a1 ^ b1 ^ bor;
        na = 1 - a1;
        bor = (na & b1) | (na & bor) | (b1 & bor);
        // bit 0 (MSB)
        int d0 = a0 ^ b0 ^ bor;
        na = 1 - a0;
        bor = (na & b0) | (na & bor) | (b0 & bor);

        v4f r;
        r[0] = (float)d0;
        r[1] = (float)d1;
        r[2] = (float)d2;
        r[3] = (float)d3;

        __builtin_nontemporal_store(r, (v4f*)res + i);
        __builtin_nontemporal_store((float)bor, borrow_out + i);
    }
}

extern "C" void kernel_launch(void* const* d_in, const int* in_sizes, int n_in,
                              void* d_out, int out_size, void* d_ws, size_t ws_size,
                              hipStream_t stream)
{
    const float* A = (const float*)d_in[0];
    const float* B = (const float*)d_in[1];
    float* out = (float*)d_out;

    int n_rows = in_sizes[0] / 4;              // (N,4) -> N rows
    float* res = out;                          // first 4*N floats: diffs
    float* borrow = out + (size_t)n_rows * 4;  // last N floats: borrow

    int blocks_needed = (n_rows + BLOCK - 1) / BLOCK;
    int grid = blocks_needed < GRID ? blocks_needed : GRID;
    Subtractor4Bit_kernel<<<grid, BLOCK, 0, stream>>>(A, B, res, borrow, n_rows);
}

// Round 8
// 320.440 us; speedup vs baseline: 1.0303x; 1.0099x over previous
//
#include <hip/hip_runtime.h>

// 4-bit ripple-borrow subtractor.
// A,B: (N,4) float32 with values in {0.0, 1.0}.
// Out: [ diffs (N,4) | borrow (N,1) ] flat float32.
// Index 3 is the LSB (reference loops i = 3..0).
//
// R8: final cell of the {flat,ILP4} x {normal,NT} matrix — ILP4 + NT.
// R2/R3's ILP regression was measured in the MALL-thrash regime (confound
// now removed by NT). NT loads carry full HBM latency (~900cy), raising the
// per-wave in-flight requirement ~4x vs the cached mix — if R5's ~4.5 TB/s
// delivered ceiling is latency x occupancy, 8 independent 16B loads per
// thread is the missing factor. Wave-blocked indexing (base + k*BLOCK)
// keeps every instruction fully coalesced. NT on all accesses (R5 regime).

constexpr int BLOCK = 256;
constexpr int RPT   = 4;   // rows per thread

typedef float v4f __attribute__((ext_vector_type(4)));

__device__ __forceinline__ void sub4(const v4f a, const v4f b,
                                     v4f& r, float& bo)
{
    // Inputs are exactly 0.0f or 1.0f.
    int a0 = (a[0] != 0.0f), a1 = (a[1] != 0.0f), a2 = (a[2] != 0.0f), a3 = (a[3] != 0.0f);
    int b0 = (b[0] != 0.0f), b1 = (b[1] != 0.0f), b2 = (b[2] != 0.0f), b3 = (b[3] != 0.0f);

    int bor = 0;
    // bit 3 (LSB)
    int d3 = a3 ^ b3 ^ bor;
    int na = 1 - a3;
    bor = (na & b3) | (na & bor) | (b3 & bor);
    // bit 2
    int d2 = a2 ^ b2 ^ bor;
    na = 1 - a2;
    bor = (na & b2) | (na & bor) | (b2 & bor);
    // bit 1
    int d1 = a1 ^ b1 ^ bor;
    na = 1 - a1;
    bor = (na & b1) | (na & bor) | (b1 & bor);
    // bit 0 (MSB)
    int d0 = a0 ^ b0 ^ bor;
    na = 1 - a0;
    bor = (na & b0) | (na & bor) | (b0 & bor);

    r[0] = (float)d0;
    r[1] = (float)d1;
    r[2] = (float)d2;
    r[3] = (float)d3;
    bo   = (float)bor;
}

__global__ __launch_bounds__(BLOCK) void Subtractor4Bit_kernel(
    const float* __restrict__ A,
    const float* __restrict__ B,
    float* __restrict__ res,
    float* __restrict__ borrow_out,
    int n_rows)
{
    int base = blockIdx.x * (BLOCK * RPT) + threadIdx.x;

    if (base + (RPT - 1) * BLOCK < n_rows) {
        // Fast path: all RPT rows valid (always taken for N = 2^23).
        v4f a[RPT], b[RPT];
#pragma unroll
        for (int k = 0; k < RPT; ++k)
            a[k] = __builtin_nontemporal_load((const v4f*)A + base + k * BLOCK);
#pragma unroll
        for (int k = 0; k < RPT; ++k)
            b[k] = __builtin_nontemporal_load((const v4f*)B + base + k * BLOCK);

#pragma unroll
        for (int k = 0; k < RPT; ++k) {
            v4f r; float bo;
            sub4(a[k], b[k], r, bo);
            __builtin_nontemporal_store(r,  (v4f*)res + base + k * BLOCK);
            __builtin_nontemporal_store(bo, borrow_out + base + k * BLOCK);
        }
    } else {
        // Tail path (never taken when n_rows % (BLOCK*RPT) == 0).
        for (int k = 0; k < RPT; ++k) {
            int i = base + k * BLOCK;
            if (i < n_rows) {
                v4f a = __builtin_nontemporal_load((const v4f*)A + i);
                v4f b = __builtin_nontemporal_load((const v4f*)B + i);
                v4f r; float bo;
                sub4(a, b, r, bo);
                __builtin_nontemporal_store(r,  (v4f*)res + i);
                __builtin_nontemporal_store(bo, borrow_out + i);
            }
        }
    }
}

extern "C" void kernel_launch(void* const* d_in, const int* in_sizes, int n_in,
                              void* d_out, int out_size, void* d_ws, size_t ws_size,
                              hipStream_t stream)
{
    const float* A = (const float*)d_in[0];
    const float* B = (const float*)d_in[1];
    float* out = (float*)d_out;

    int n_rows = in_sizes[0] / 4;              // (N,4) -> N rows
    float* res = out;                          // first 4*N floats: diffs
    float* borrow = out + (size_t)n_rows * 4;  // last N floats: borrow

    int rows_per_block = BLOCK * RPT;
    int grid = (n_rows + rows_per_block - 1) / rows_per_block;
    Subtractor4Bit_kernel<<<grid, BLOCK, 0, stream>>>(A, B, res, borrow, n_rows);
}

// Round 9
// 317.349 us; speedup vs baseline: 1.0403x; 1.0097x over previous
//
#include <hip/hip_runtime.h>

// 4-bit ripple-borrow subtractor, one thread per row (flat shape).
// A,B: (N,4) float32 with values in {0.0, 1.0}.
// Out: [ diffs (N,4) | borrow (N,1) ] flat float32.
// Index 3 is the LSB (reference loops i = 3..0).
//
// R9 = R5 revert (measured best: harness 316.3, kernel ~95us, 4.59 TB/s
// delivered). Full lever matrix tested and nulled:
//   - MLP/ILP4 (R2/R3/R8): neutral-to-harmful — queues already saturated.
//   - NT loads (R4): +15% — removed 268MB input MALL-thrash churn. KEEP.
//   - NT stores (R5): +5% — removed write-allocate churn. KEEP.
//   - A-retained-in-MALL (R6): -134MB HBM bytes, ZERO time change ->
//     bytes aren't the limit; the CU<->fabric request path is.
//   - Persistent grid (R7): neutral — endpgm drain/dispatch churn not a cost.
// Conclusion: ~4.6 TB/s is this chip's delivered ceiling for the mandatory
// 4-stream 2R+2W pattern (copy/fill references are 1-2 stream shapes).
// 436 MB / 4.6 TB/s ~= 95 us = the pattern roofline.

constexpr int BLOCK = 256;

typedef float v4f __attribute__((ext_vector_type(4)));

__global__ __launch_bounds__(BLOCK) void Subtractor4Bit_kernel(
    const float* __restrict__ A,
    const float* __restrict__ B,
    float* __restrict__ res,
    float* __restrict__ borrow_out,
    int n_rows)
{
    int i = blockIdx.x * BLOCK + threadIdx.x;
    if (i >= n_rows) return;

    v4f a = __builtin_nontemporal_load((const v4f*)A + i);
    v4f b = __builtin_nontemporal_load((const v4f*)B + i);

    // Convert to 0/1 ints (inputs are exactly 0.0f or 1.0f).
    int a0 = (a[0] != 0.0f), a1 = (a[1] != 0.0f), a2 = (a[2] != 0.0f), a3 = (a[3] != 0.0f);
    int b0 = (b[0] != 0.0f), b1 = (b[1] != 0.0f), b2 = (b[2] != 0.0f), b3 = (b[3] != 0.0f);

    int bor = 0;
    // bit 3 (LSB)
    int d3 = a3 ^ b3 ^ bor;
    int na = 1 - a3;
    bor = (na & b3) | (na & bor) | (b3 & bor);
    // bit 2
    int d2 = a2 ^ b2 ^ bor;
    na = 1 - a2;
    bor = (na & b2) | (na & bor) | (b2 & bor);
    // bit 1
    int d1 = a1 ^ b1 ^ bor;
    na = 1 - a1;
    bor = (na & b1) | (na & bor) | (b1 & bor);
    // bit 0 (MSB)
    int d0 = a0 ^ b0 ^ bor;
    na = 1 - a0;
    bor = (na & b0) | (na & bor) | (b0 & bor);

    v4f r;
    r[0] = (float)d0;
    r[1] = (float)d1;
    r[2] = (float)d2;
    r[3] = (float)d3;

    __builtin_nontemporal_store(r, (v4f*)res + i);
    __builtin_nontemporal_store((float)bor, borrow_out + i);
}

extern "C" void kernel_launch(void* const* d_in, const int* in_sizes, int n_in,
                              void* d_out, int out_size, void* d_ws, size_t ws_size,
                              hipStream_t stream)
{
    const float* A = (const float*)d_in[0];
    const float* B = (const float*)d_in[1];
    float* out = (float*)d_out;

    int n_rows = in_sizes[0] / 4;              // (N,4) -> N rows
    float* res = out;                          // first 4*N floats: diffs
    float* borrow = out + (size_t)n_rows * 4;  // last N floats: borrow

    int grid = (n_rows + BLOCK - 1) / BLOCK;
    Subtractor4Bit_kernel<<<grid, BLOCK, 0, stream>>>(A, B, res, borrow, n_rows);
}